// Round 1
// baseline (37.013 us; speedup 1.0000x reference)
//
#include <hip/hip_runtime.h>
#include <math.h>

#define NB 32
#define NH 168
#define ND 512
#define NHIST 336
#define NFORE 168
#define NL 504
#define NF 8

__device__ inline float waveSum(float v) {
    #pragma unroll
    for (int m = 1; m < 64; m <<= 1) v += __shfl_xor(v, m, 64);
    return v;
}
__device__ inline float waveMax(float v) {
    #pragma unroll
    for (int m = 1; m < 64; m <<= 1) v = fmaxf(v, __shfl_xor(v, m, 64));
    return v;
}
__device__ inline float waveMin(float v) {
    #pragma unroll
    for (int m = 1; m < 64; m <<= 1) v = fminf(v, __shfl_xor(v, m, 64));
    return v;
}

// K1: precompute uk[d] = sum_e Wk[e]*Wq[e,d]; wvs[e] = Ws[e,:]·Wv;
//     bvs[e] = 8*(Ws[e,:]·bv) + bs[e]; ck = bq·Wk.
__global__ __launch_bounds__(512) void k_pre(
        const float* __restrict__ Wq, const float* __restrict__ bq,
        const float* __restrict__ Wk, const float* __restrict__ Wv,
        const float* __restrict__ bv, const float* __restrict__ Ws,
        const float* __restrict__ bs,
        float* __restrict__ uk, float* __restrict__ wvs,
        float* __restrict__ bvs, float* __restrict__ ckp) {
    const int blk = blockIdx.x;
    const int tid = threadIdx.x;
    const int lane = tid & 63, w = tid >> 6;
    __shared__ float lds[8 * 64];
    if (blk < 8) {
        // uk columns [blk*64, blk*64+64): column-reduce over e, coalesced rows
        const int col = blk * 64 + lane;
        float acc = 0.f;
        #pragma unroll 4
        for (int r = 0; r < 64; ++r) {
            const int e = w + 8 * r;
            acc += Wk[e] * Wq[e * ND + col];
        }
        lds[w * 64 + lane] = acc;
        __syncthreads();
        if (tid < 64) {
            float s = 0.f;
            #pragma unroll
            for (int i = 0; i < 8; ++i) s += lds[i * 64 + tid];
            uk[blk * 64 + tid] = s;
        }
    } else if (blk < 72) {
        // one wave per row e: wvs / bvs
        const int e = (blk - 8) * 8 + w;
        float a1 = 0.f, a2 = 0.f;
        #pragma unroll
        for (int k = 0; k < 8; ++k) {
            const int d = lane + 64 * k;
            const float x = Ws[e * ND + d];
            a1 += x * Wv[d];
            a2 += x * bv[d];
        }
        a1 = waveSum(a1);
        a2 = waveSum(a2);
        if (lane == 0) { wvs[e] = a1; bvs[e] = 8.f * a2 + bs[e]; }
    } else {
        float p = (tid < ND) ? bq[tid] * Wk[tid] : 0.f;
        p = waveSum(p);
        if (lane == 0) lds[w] = p;
        __syncthreads();
        if (tid == 0) {
            float s = 0.f;
            #pragma unroll
            for (int i = 0; i < 8; ++i) s += lds[i];
            *ckp = s;
        }
    }
}

// K2: per-(b,h) wave: a = (y·uk + ck)/scale; S = sum_f softmax-weighted mean of
//     full[b,:,f]; logit = (S*(y·wvs) + y·bvs)/scale.
__global__ __launch_bounds__(256) void k_main(
        const float* __restrict__ y, const float* __restrict__ wh,
        const float* __restrict__ wf,
        const float* __restrict__ uk, const float* __restrict__ wvs,
        const float* __restrict__ bvs, const float* __restrict__ ckp,
        float* __restrict__ logits) {
    const int b = blockIdx.x / 42, hg = blockIdx.x % 42;
    const int tid = threadIdx.x, lane = tid & 63, w = tid >> 6;
    __shared__ float xT[NF][512];      // transposed weather: conflict-free reads
    __shared__ float xmx[NF], xmn[NF];

    // stage full[b] = concat(hist, fore) transposed into LDS
    for (int i = tid; i < NL * NF; i += 256) {
        const int l = i >> 3, f = i & 7;
        const float v = (l < NHIST) ? wh[(b * NHIST + l) * NF + f]
                                    : wf[(b * NFORE + (l - NHIST)) * NF + f];
        xT[f][l] = v;
    }
    __syncthreads();
    // per-f min/max (for exact stable softmax max: m = a>0 ? a*max : a*min)
    for (int f = w; f < NF; f += 4) {
        float mx = -1e30f, mn = 1e30f;
        #pragma unroll
        for (int k = 0; k < 8; ++k) {
            const int idx = lane + 64 * k;
            if (idx < NL) {
                const float v = xT[f][idx];
                mx = fmaxf(mx, v); mn = fminf(mn, v);
            }
        }
        mx = waveMax(mx); mn = waveMin(mn);
        if (lane == 0) { xmx[f] = mx; xmn[f] = mn; }
    }
    __syncthreads();

    const int h = hg * 4 + w;
    const float scale = 22.627416997969522f;  // sqrt(512)
    const float* __restrict__ yrow = y + (size_t)(b * NH + h) * ND;
    float d1 = 0.f, d2 = 0.f, d3 = 0.f;
    #pragma unroll
    for (int k = 0; k < 8; ++k) {
        const int d = lane + 64 * k;
        const float yv = yrow[d];
        d1 += yv * uk[d];
        d2 += yv * wvs[d];
        d3 += yv * bvs[d];
    }
    d1 = waveSum(d1); d2 = waveSum(d2); d3 = waveSum(d3);
    const float a = (d1 + *ckp) / scale;

    float S = 0.f;
    #pragma unroll
    for (int f = 0; f < NF; ++f) {
        const float m = (a >= 0.f) ? a * xmx[f] : a * xmn[f];
        float num = 0.f, den = 0.f;
        #pragma unroll
        for (int k = 0; k < 8; ++k) {
            const int idx = lane + 64 * k;
            if (idx < NL) {
                const float x = xT[f][idx];
                const float e = __expf(a * x - m);
                den += e;
                num += x * e;
            }
        }
        num = waveSum(num); den = waveSum(den);
        S += num / den;
    }
    if (lane == 0) logits[b * NH + h] = (S * d2 + d3) / scale;
}

// K3: per (b, 64-wide d-chunk): softmax over H, final[d] = sum_h P[h]*y[b,h,d],
//     out[b,h,d] = y[b,h,d] + final[d].
__global__ __launch_bounds__(512) void k_final(
        const float* __restrict__ y, const float* __restrict__ logits,
        float* __restrict__ out) {
    const int b = blockIdx.x >> 3, dc = blockIdx.x & 7;
    const int dbase = dc * 64;
    const int tid = threadIdx.x, lane = tid & 63, w = tid >> 6;
    __shared__ float lg[NH];
    __shared__ float mz[2];
    __shared__ float fl[8][64];
    if (tid < NH) lg[tid] = logits[b * NH + tid];
    __syncthreads();
    if (w == 0) {
        float mx = -1e30f;
        for (int i = lane; i < NH; i += 64) mx = fmaxf(mx, lg[i]);
        mx = waveMax(mx);
        float z = 0.f;
        for (int i = lane; i < NH; i += 64) z += __expf(lg[i] - mx);
        z = waveSum(z);
        if (lane == 0) { mz[0] = mx; mz[1] = z; }
    }
    __syncthreads();
    const float mx = mz[0], invz = 1.f / mz[1];
    float facc = 0.f;
    for (int h = w; h < NH; h += 8) {
        const float P = __expf(lg[h] - mx) * invz;
        facc += P * y[(size_t)(b * NH + h) * ND + dbase + lane];
    }
    fl[w][lane] = facc;
    __syncthreads();
    if (tid < 64) {
        float s = 0.f;
        #pragma unroll
        for (int i = 0; i < 8; ++i) s += fl[i][tid];
        fl[0][tid] = s;
    }
    __syncthreads();
    const float fin = fl[0][lane];
    for (int h = w; h < NH; h += 8) {
        const size_t idx = (size_t)(b * NH + h) * ND + dbase + lane;
        out[idx] = y[idx] + fin;
    }
}

extern "C" void kernel_launch(void* const* d_in, const int* in_sizes, int n_in,
                              void* d_out, int out_size, void* d_ws, size_t ws_size,
                              hipStream_t stream) {
    const float* y  = (const float*)d_in[0];
    const float* wh = (const float*)d_in[1];
    const float* wf = (const float*)d_in[2];
    const float* Wq = (const float*)d_in[3];
    const float* bq = (const float*)d_in[4];
    const float* Wk = (const float*)d_in[5];
    // d_in[6] = bk: cancels in the softmax over L — unused.
    const float* Wv = (const float*)d_in[7];
    const float* bv = (const float*)d_in[8];
    const float* Ws = (const float*)d_in[9];
    const float* bs = (const float*)d_in[10];
    float* out = (float*)d_out;
    float* ws = (float*)d_ws;

    float* uk     = ws;            // 512
    float* wvs    = ws + 512;      // 512
    float* bvs    = ws + 1024;     // 512
    float* ckp    = ws + 1536;     // 1
    float* logits = ws + 1600;     // B*H = 5376

    k_pre<<<73, 512, 0, stream>>>(Wq, bq, Wk, Wv, bv, Ws, bs, uk, wvs, bvs, ckp);
    k_main<<<NB * 42, 256, 0, stream>>>(y, wh, wf, uk, wvs, bvs, ckp, logits);
    k_final<<<NB * 8, 512, 0, stream>>>(y, logits, out);
}

// Round 2
// 31.277 us; speedup vs baseline: 1.1834x; 1.1834x over previous
//
#include <hip/hip_runtime.h>
#include <math.h>

#define NB 32
#define NH 168
#define ND 512
#define NHIST 336
#define NFORE 168
#define NL 504
#define NF 8

__device__ inline float waveSum(float v) {
    #pragma unroll
    for (int m = 1; m < 64; m <<= 1) v += __shfl_xor(v, m, 64);
    return v;
}
__device__ inline float waveMax(float v) {
    #pragma unroll
    for (int m = 1; m < 64; m <<= 1) v = fmaxf(v, __shfl_xor(v, m, 64));
    return v;
}
__device__ inline float waveMin(float v) {
    #pragma unroll
    for (int m = 1; m < 64; m <<= 1) v = fminf(v, __shfl_xor(v, m, 64));
    return v;
}
// 3-step butterfly within 8-lane group
__device__ inline float grpSum(float v) {
    v += __shfl_xor(v, 1, 64);
    v += __shfl_xor(v, 2, 64);
    v += __shfl_xor(v, 4, 64);
    return v;
}

// K1 (16 blocks x 512 thr):
//  blk 0..7 : uk[d] = sum_e Wk[e]*Wq[e,d], 64 cols/block, full-ILP over e
//  blk 8..15: wvs[e] = Ws[e,:]·Wv; bvs[e] = 8*(Ws[e,:]·bv) + bs[e]  (8-lane dots)
//  blk 8 also: ck = bq·Wk
__global__ __launch_bounds__(512) void k_pre(
        const float* __restrict__ Wq, const float* __restrict__ bq,
        const float* __restrict__ Wk, const float* __restrict__ Wv,
        const float* __restrict__ bv, const float* __restrict__ Ws,
        const float* __restrict__ bs,
        float* __restrict__ uk, float* __restrict__ wvs,
        float* __restrict__ bvs, float* __restrict__ ckp) {
    const int blk = blockIdx.x;
    const int tid = threadIdx.x;
    const int lane = tid & 63, w = tid >> 6;     // w: 0..7
    __shared__ float lds[512];
    if (blk < 8) {
        const int col = (blk << 6) + lane;
        float acc = 0.f;
        #pragma unroll 16
        for (int r = 0; r < 64; ++r) {
            const int e = w + 8 * r;
            acc += Wk[e] * Wq[e * ND + col];
        }
        lds[w * 64 + lane] = acc;
        __syncthreads();
        if (tid < 64) {
            float s = 0.f;
            #pragma unroll
            for (int i = 0; i < 8; ++i) s += lds[i * 64 + tid];
            uk[(blk << 6) + tid] = s;
        }
    } else {
        const int g = lane >> 3, sl = lane & 7;
        const int e = ((blk - 8) << 6) + (w << 3) + g;   // 0..511
        const float4* __restrict__ wsr = (const float4*)(Ws + (size_t)e * ND);
        const float4* __restrict__ wv4 = (const float4*)Wv;
        const float4* __restrict__ bv4 = (const float4*)bv;
        float a1 = 0.f, a2 = 0.f;
        #pragma unroll
        for (int i = 0; i < 16; ++i) {
            const int q = sl + 8 * i;
            const float4 x = wsr[q];
            const float4 v = wv4[q];
            const float4 c = bv4[q];
            a1 += x.x * v.x + x.y * v.y + x.z * v.z + x.w * v.w;
            a2 += x.x * c.x + x.y * c.y + x.z * c.z + x.w * c.w;
        }
        a1 = grpSum(a1);
        a2 = grpSum(a2);
        if (sl == 0) { wvs[e] = a1; bvs[e] = 8.f * a2 + bs[e]; }
        if (blk == 8) {
            float p = bq[tid] * Wk[tid];
            p = waveSum(p);
            if (lane == 0) lds[w] = p;
            __syncthreads();
            if (tid == 0) {
                float s = 0.f;
                #pragma unroll
                for (int i = 0; i < 8; ++i) s += lds[i];
                *ckp = s;
            }
        }
    }
}

// K2 (192 blocks x 256 thr): 8 lanes per h, 8 h per wave, 32 h per block.
//  a = (y·uk + ck)/scale; S = sum_f softmax_l-weighted mean of full[b,:,f];
//  logit = (S*(y·wvs) + y·bvs)/scale.
__global__ __launch_bounds__(256) void k_main(
        const float* __restrict__ y, const float* __restrict__ wh,
        const float* __restrict__ wf,
        const float* __restrict__ uk, const float* __restrict__ wvs,
        const float* __restrict__ bvs, const float* __restrict__ ckp,
        float* __restrict__ logits) {
    const int b = blockIdx.x / 6, hb = blockIdx.x % 6;
    const int tid = threadIdx.x, lane = tid & 63, w = tid >> 6;
    const int g = lane >> 3, sl = lane & 7;
    __shared__ float xT[NF][NL];          // transposed weather, 16.1 KB
    __shared__ float xmx[NF], xmn[NF];

    // stage full[b] transposed (coalesced global reads; 2-way LDS write alias = free)
    for (int i = tid; i < NL * NF; i += 256) {
        const int l = i >> 3, f = i & 7;
        const float v = (l < NHIST) ? wh[(b * NHIST + l) * NF + f]
                                    : wf[(b * NFORE + (l - NHIST)) * NF + f];
        xT[f][l] = v;
    }
    __syncthreads();
    for (int f = w; f < NF; f += 4) {
        float mx = -1e30f, mn = 1e30f;
        #pragma unroll
        for (int j = 0; j < 8; ++j) {
            const int idx = lane + 64 * j;
            if (idx < NL) {
                const float v = xT[f][idx];
                mx = fmaxf(mx, v); mn = fminf(mn, v);
            }
        }
        mx = waveMax(mx); mn = waveMin(mn);
        if (lane == 0) { xmx[f] = mx; xmn[f] = mn; }
    }
    __syncthreads();

    const int h = hb * 32 + w * 8 + g;          // up to 191, guarded below
    const int hc = (h < NH) ? h : (NH - 1);
    const float scale = 22.627416997969522f;    // sqrt(512)
    const float4* __restrict__ yr = (const float4*)(y + ((size_t)b * NH + hc) * ND);
    const float4* __restrict__ uk4 = (const float4*)uk;
    const float4* __restrict__ wv4 = (const float4*)wvs;
    const float4* __restrict__ bv4 = (const float4*)bvs;
    float d1 = 0.f, d2 = 0.f, d3 = 0.f;
    #pragma unroll
    for (int i = 0; i < 16; ++i) {
        const int q = sl + 8 * i;               // 128B-contiguous per 8-lane group
        const float4 yv = yr[q];
        const float4 u = uk4[q];
        const float4 v = wv4[q];
        const float4 c = bv4[q];
        d1 += yv.x * u.x + yv.y * u.y + yv.z * u.z + yv.w * u.w;
        d2 += yv.x * v.x + yv.y * v.y + yv.z * v.z + yv.w * v.w;
        d3 += yv.x * c.x + yv.y * c.y + yv.z * c.z + yv.w * c.w;
    }
    d1 = grpSum(d1); d2 = grpSum(d2); d3 = grpSum(d3);
    const float a = (d1 + *ckp) / scale;

    float S = 0.f;
    #pragma unroll
    for (int f = 0; f < NF; ++f) {
        const float m = (a >= 0.f) ? a * xmx[f] : a * xmn[f];
        const float4* __restrict__ xp = (const float4*)&xT[f][0];  // 126 float4s
        float num = 0.f, den = 0.f;
        #pragma unroll
        for (int i = 0; i < 16; ++i) {
            const int q = sl + 8 * i;
            if (q < 126) {                      // 504 = 126*4
                const float4 x = xp[q];         // wave-uniform -> LDS broadcast
                float e0 = __expf(fmaf(a, x.x, -m));
                float e1 = __expf(fmaf(a, x.y, -m));
                float e2 = __expf(fmaf(a, x.z, -m));
                float e3 = __expf(fmaf(a, x.w, -m));
                den += (e0 + e1) + (e2 + e3);
                num += x.x * e0 + x.y * e1 + x.z * e2 + x.w * e3;
            }
        }
        num = grpSum(num); den = grpSum(den);
        S += num / den;
    }
    if (sl == 0 && h < NH) logits[b * NH + h] = (S * d2 + d3) / scale;
}

// K3 (256 blocks x 512 thr): per (b, 64-wide d-chunk): softmax over H,
// final[d] = sum_h P[h]*y[b,h,d], out = y + final. y kept in regs (no re-read).
__global__ __launch_bounds__(512) void k_final(
        const float* __restrict__ y, const float* __restrict__ logits,
        float* __restrict__ out) {
    const int b = blockIdx.x >> 3, dbase = (blockIdx.x & 7) << 6;
    const int tid = threadIdx.x, lane = tid & 63, w = tid >> 6;
    __shared__ float lg[NH];
    __shared__ float mz[2];
    __shared__ float fl[8][64];
    if (tid < NH) lg[tid] = logits[b * NH + tid];
    __syncthreads();
    if (w == 0) {
        float mx = -1e30f;
        for (int i = lane; i < NH; i += 64) mx = fmaxf(mx, lg[i]);
        mx = waveMax(mx);
        float z = 0.f;
        for (int i = lane; i < NH; i += 64) z += __expf(lg[i] - mx);
        z = waveSum(z);
        if (lane == 0) { mz[0] = mx; mz[1] = z; }
    }
    __syncthreads();
    const float mx = mz[0], invz = 1.f / mz[1];
    float yv[21];
    float facc = 0.f;
    #pragma unroll
    for (int k = 0; k < 21; ++k) {             // h = w + 8k covers 0..167 exactly
        const int h = w + 8 * k;
        yv[k] = y[((size_t)b * NH + h) * ND + dbase + lane];
        facc += __expf(lg[h] - mx) * invz * yv[k];
    }
    fl[w][lane] = facc;
    __syncthreads();
    if (tid < 64) {
        float s = 0.f;
        #pragma unroll
        for (int i = 0; i < 8; ++i) s += fl[i][tid];
        fl[0][tid] = s;
    }
    __syncthreads();
    const float fin = fl[0][lane];
    #pragma unroll
    for (int k = 0; k < 21; ++k) {
        const int h = w + 8 * k;
        out[((size_t)b * NH + h) * ND + dbase + lane] = yv[k] + fin;
    }
}

extern "C" void kernel_launch(void* const* d_in, const int* in_sizes, int n_in,
                              void* d_out, int out_size, void* d_ws, size_t ws_size,
                              hipStream_t stream) {
    const float* y  = (const float*)d_in[0];
    const float* wh = (const float*)d_in[1];
    const float* wf = (const float*)d_in[2];
    const float* Wq = (const float*)d_in[3];
    const float* bq = (const float*)d_in[4];
    const float* Wk = (const float*)d_in[5];
    // d_in[6] = bk: cancels in the softmax over L — unused.
    const float* Wv = (const float*)d_in[7];
    const float* bv = (const float*)d_in[8];
    const float* Ws = (const float*)d_in[9];
    const float* bs = (const float*)d_in[10];
    float* out = (float*)d_out;
    float* ws = (float*)d_ws;

    float* uk     = ws;            // 512
    float* wvs    = ws + 512;      // 512
    float* bvs    = ws + 1024;     // 512
    float* ckp    = ws + 1536;     // 1
    float* logits = ws + 1600;     // B*H = 5376

    k_pre<<<16, 512, 0, stream>>>(Wq, bq, Wk, Wv, bv, Ws, bs, uk, wvs, bvs, ckp);
    k_main<<<NB * 6, 256, 0, stream>>>(y, wh, wf, uk, wvs, bvs, ckp, logits);
    k_final<<<NB * 8, 512, 0, stream>>>(y, logits, out);
}

// Round 3
// 29.358 us; speedup vs baseline: 1.2608x; 1.0654x over previous
//
#include <hip/hip_runtime.h>
#include <math.h>

#define NB 32
#define NH 168
#define ND 512
#define NHIST 336
#define NFORE 168
#define NL 504
#define NF 8

__device__ inline float waveSum(float v) {
    #pragma unroll
    for (int m = 1; m < 64; m <<= 1) v += __shfl_xor(v, m, 64);
    return v;
}
__device__ inline float waveMax(float v) {
    #pragma unroll
    for (int m = 1; m < 64; m <<= 1) v = fmaxf(v, __shfl_xor(v, m, 64));
    return v;
}
__device__ inline float waveMin(float v) {
    #pragma unroll
    for (int m = 1; m < 64; m <<= 1) v = fminf(v, __shfl_xor(v, m, 64));
    return v;
}
__device__ inline float grpSum16(float v) {
    v += __shfl_xor(v, 1, 64);
    v += __shfl_xor(v, 2, 64);
    v += __shfl_xor(v, 4, 64);
    v += __shfl_xor(v, 8, 64);
    return v;
}
__device__ inline float grpSum32(float v) {
    v += __shfl_xor(v, 1, 64);
    v += __shfl_xor(v, 2, 64);
    v += __shfl_xor(v, 4, 64);
    v += __shfl_xor(v, 8, 64);
    v += __shfl_xor(v, 16, 64);
    return v;
}

// K1 (49 blocks x 512):
//  blk 0..15 : uk[col] = sum_e Wk[e]*Wq[e,col], 32 cols/block
//  blk 16..47: wvs[e] = Ws[e,:]·Wv; bvs[e] = 8*(Ws[e,:]·bv)+bs[e], 16 rows/block
//  blk 48    : ck = bq·Wk
__global__ __launch_bounds__(512) void k_pre(
        const float* __restrict__ Wq, const float* __restrict__ bq,
        const float* __restrict__ Wk, const float* __restrict__ Wv,
        const float* __restrict__ bv, const float* __restrict__ Ws,
        const float* __restrict__ bs,
        float* __restrict__ uk, float* __restrict__ wvs,
        float* __restrict__ bvs, float* __restrict__ ckp) {
    const int blk = blockIdx.x;
    const int tid = threadIdx.x;
    __shared__ float lds[512];
    if (blk < 16) {
        const int col = tid & 31, rg = tid >> 5;       // rg: 0..15
        const int colbase = blk << 5;
        float acc = 0.f;
        #pragma unroll
        for (int r = 0; r < 32; ++r) {
            const int e = rg + 16 * r;
            acc += Wk[e] * Wq[e * ND + colbase + col];
        }
        lds[rg * 32 + col] = acc;
        __syncthreads();
        if (tid < 32) {
            float s = 0.f;
            #pragma unroll
            for (int i = 0; i < 16; ++i) s += lds[i * 32 + tid];
            uk[colbase + tid] = s;
        }
    } else if (blk < 48) {
        const int g = tid >> 5, sl = tid & 31;          // 16 rows, 32 lanes each
        const int e = ((blk - 16) << 4) + g;
        const float4* __restrict__ wsr = (const float4*)(Ws + (size_t)e * ND);
        const float4* __restrict__ wv4 = (const float4*)Wv;
        const float4* __restrict__ bv4 = (const float4*)bv;
        float a1 = 0.f, a2 = 0.f;
        #pragma unroll
        for (int i = 0; i < 4; ++i) {
            const int q = sl + 32 * i;
            const float4 x = wsr[q];
            const float4 v = wv4[q];
            const float4 c = bv4[q];
            a1 += x.x * v.x + x.y * v.y + x.z * v.z + x.w * v.w;
            a2 += x.x * c.x + x.y * c.y + x.z * c.z + x.w * c.w;
        }
        a1 = grpSum32(a1);
        a2 = grpSum32(a2);
        if (sl == 0) { wvs[e] = a1; bvs[e] = 8.f * a2 + bs[e]; }
    } else {
        const int lane = tid & 63, w = tid >> 6;
        float p = bq[tid] * Wk[tid];
        p = waveSum(p);
        if (lane == 0) lds[w] = p;
        __syncthreads();
        if (tid == 0) {
            float s = 0.f;
            #pragma unroll
            for (int i = 0; i < 8; ++i) s += lds[i];
            *ckp = s;
        }
    }
}

// K2 (352 blocks x 256): 16 lanes per h, 16 h per block.
__global__ __launch_bounds__(256) void k_main(
        const float* __restrict__ y, const float* __restrict__ wh,
        const float* __restrict__ wf,
        const float* __restrict__ uk, const float* __restrict__ wvs,
        const float* __restrict__ bvs, const float* __restrict__ ckp,
        float* __restrict__ logits) {
    const int b = blockIdx.x / 11, hb = blockIdx.x % 11;
    const int tid = threadIdx.x, lane = tid & 63, w = tid >> 6;
    const int g = lane >> 4, sl = lane & 15;
    __shared__ float xT[NF][NL];
    __shared__ float xmx[NF], xmn[NF];

    for (int i = tid; i < NL * NF; i += 256) {
        const int l = i >> 3, f = i & 7;
        const float v = (l < NHIST) ? wh[(b * NHIST + l) * NF + f]
                                    : wf[(b * NFORE + (l - NHIST)) * NF + f];
        xT[f][l] = v;
    }
    __syncthreads();
    for (int f = w; f < NF; f += 4) {
        float mx = -1e30f, mn = 1e30f;
        #pragma unroll
        for (int j = 0; j < 8; ++j) {
            const int idx = lane + 64 * j;
            if (idx < NL) {
                const float v = xT[f][idx];
                mx = fmaxf(mx, v); mn = fminf(mn, v);
            }
        }
        mx = waveMax(mx); mn = waveMin(mn);
        if (lane == 0) { xmx[f] = mx; xmn[f] = mn; }
    }
    __syncthreads();

    const int h = hb * 16 + w * 4 + g;           // up to 175, guarded
    const int hc = (h < NH) ? h : (NH - 1);
    const float scale = 22.627416997969522f;     // sqrt(512)
    const float4* __restrict__ yr = (const float4*)(y + ((size_t)b * NH + hc) * ND);
    const float4* __restrict__ uk4 = (const float4*)uk;
    const float4* __restrict__ wv4 = (const float4*)wvs;
    const float4* __restrict__ bv4 = (const float4*)bvs;
    float d1 = 0.f, d2 = 0.f, d3 = 0.f;
    #pragma unroll
    for (int i = 0; i < 8; ++i) {
        const int q = sl + 16 * i;               // 256B-contiguous per 16-lane group
        const float4 yv = yr[q];
        const float4 u = uk4[q];
        const float4 v = wv4[q];
        const float4 c = bv4[q];
        d1 += yv.x * u.x + yv.y * u.y + yv.z * u.z + yv.w * u.w;
        d2 += yv.x * v.x + yv.y * v.y + yv.z * v.z + yv.w * v.w;
        d3 += yv.x * c.x + yv.y * c.y + yv.z * c.z + yv.w * c.w;
    }
    d1 = grpSum16(d1); d2 = grpSum16(d2); d3 = grpSum16(d3);
    const float a = (d1 + *ckp) / scale;

    float S = 0.f;
    #pragma unroll
    for (int f = 0; f < NF; ++f) {
        const float m = (a >= 0.f) ? a * xmx[f] : a * xmn[f];
        const float4* __restrict__ xp = (const float4*)&xT[f][0];  // 126 float4s
        float num = 0.f, den = 0.f;
        #pragma unroll
        for (int i = 0; i < 8; ++i) {
            const int q = sl + 16 * i;
            if (q < 126) {
                const float4 x = xp[q];
                float e0 = __expf(fmaf(a, x.x, -m));
                float e1 = __expf(fmaf(a, x.y, -m));
                float e2 = __expf(fmaf(a, x.z, -m));
                float e3 = __expf(fmaf(a, x.w, -m));
                den += (e0 + e1) + (e2 + e3);
                num += x.x * e0 + x.y * e1 + x.z * e2 + x.w * e3;
            }
        }
        num = grpSum16(num); den = grpSum16(den);
        S += num / den;
    }
    if (sl == 0 && h < NH) logits[b * NH + h] = (S * d2 + d3) / scale;
}

// K3 (256 blocks x 512): per (b, 64-wide d-chunk), float4-vectorized.
__global__ __launch_bounds__(512) void k_final(
        const float* __restrict__ y, const float* __restrict__ logits,
        float* __restrict__ out) {
    const int b = blockIdx.x >> 3, dc = blockIdx.x & 7;
    const int tid = threadIdx.x, lane = tid & 63, w = tid >> 6;
    const int c = tid & 15, hw = tid >> 4;        // float4 col 0..15, h-group 0..31
    __shared__ float lg[NH];
    __shared__ float mz[2];
    __shared__ float4 fl[8][16];
    __shared__ float4 ffin[16];
    if (tid < NH) lg[tid] = logits[b * NH + tid];
    __syncthreads();
    if (w == 0) {
        float mx = -1e30f;
        for (int i = lane; i < NH; i += 64) mx = fmaxf(mx, lg[i]);
        mx = waveMax(mx);
        float z = 0.f;
        for (int i = lane; i < NH; i += 64) z += __expf(lg[i] - mx);
        z = waveSum(z);
        if (lane == 0) { mz[0] = mx; mz[1] = 1.f / z; }
    }
    __syncthreads();
    const float mx = mz[0], invz = mz[1];
    if (tid < NH) lg[tid] = __expf(lg[tid] - mx) * invz;   // lg := P
    __syncthreads();

    const float4* __restrict__ y4 = (const float4*)y;      // 128 float4 per row
    const size_t rowbase = ((size_t)b * NH) * 128 + dc * 16 + c;
    float4 yv[6];
    float4 acc = make_float4(0.f, 0.f, 0.f, 0.f);
    #pragma unroll
    for (int k = 0; k < 6; ++k) {
        const int h = hw + 32 * k;
        if (h < NH) {
            yv[k] = y4[rowbase + (size_t)h * 128];
            const float P = lg[h];
            acc.x += P * yv[k].x; acc.y += P * yv[k].y;
            acc.z += P * yv[k].z; acc.w += P * yv[k].w;
        }
    }
    // reduce over the 4 h-groups within each wave (lane-group stride 16)
    #pragma unroll
    for (int m = 16; m < 64; m <<= 1) {
        acc.x += __shfl_xor(acc.x, m, 64);
        acc.y += __shfl_xor(acc.y, m, 64);
        acc.z += __shfl_xor(acc.z, m, 64);
        acc.w += __shfl_xor(acc.w, m, 64);
    }
    if (lane < 16) fl[w][lane] = acc;
    __syncthreads();
    if (tid < 16) {
        float4 s = fl[0][tid];
        #pragma unroll
        for (int i = 1; i < 8; ++i) {
            const float4 t = fl[i][tid];
            s.x += t.x; s.y += t.y; s.z += t.z; s.w += t.w;
        }
        ffin[tid] = s;
    }
    __syncthreads();
    const float4 fin = ffin[c];
    float4* __restrict__ out4 = (float4*)out;
    #pragma unroll
    for (int k = 0; k < 6; ++k) {
        const int h = hw + 32 * k;
        if (h < NH) {
            float4 o = yv[k];
            o.x += fin.x; o.y += fin.y; o.z += fin.z; o.w += fin.w;
            out4[rowbase + (size_t)h * 128] = o;
        }
    }
}

extern "C" void kernel_launch(void* const* d_in, const int* in_sizes, int n_in,
                              void* d_out, int out_size, void* d_ws, size_t ws_size,
                              hipStream_t stream) {
    const float* y  = (const float*)d_in[0];
    const float* wh = (const float*)d_in[1];
    const float* wf = (const float*)d_in[2];
    const float* Wq = (const float*)d_in[3];
    const float* bq = (const float*)d_in[4];
    const float* Wk = (const float*)d_in[5];
    // d_in[6] = bk: cancels in the softmax over L — unused.
    const float* Wv = (const float*)d_in[7];
    const float* bv = (const float*)d_in[8];
    const float* Ws = (const float*)d_in[9];
    const float* bs = (const float*)d_in[10];
    float* out = (float*)d_out;
    float* ws = (float*)d_ws;

    float* uk     = ws;            // 512
    float* wvs    = ws + 512;      // 512
    float* bvs    = ws + 1024;     // 512
    float* ckp    = ws + 1536;     // 1
    float* logits = ws + 1600;     // B*H = 5376

    k_pre<<<49, 512, 0, stream>>>(Wq, bq, Wk, Wv, bv, Ws, bs, uk, wvs, bvs, ckp);
    k_main<<<NB * 11, 256, 0, stream>>>(y, wh, wf, uk, wvs, bvs, ckp, logits);
    k_final<<<NB * 8, 512, 0, stream>>>(y, logits, out);
}